// Round 1
// baseline (1386.065 us; speedup 1.0000x reference)
//
#include <hip/hip_runtime.h>
#include <hip/hip_bf16.h>
#include <math.h>
#include <stdint.h>

// Problem constants
#define B_ 16
#define N_ 4096
#define C_ 384
#define H_ 8
#define NH_ 512

typedef __attribute__((ext_vector_type(8))) short short8;
typedef __attribute__((ext_vector_type(4))) float f32x4;

__device__ __forceinline__ unsigned short f2bf(float x) {
  uint32_t u = __builtin_bit_cast(uint32_t, x);
  uint32_t r = (u + 0x7fffu + ((u >> 16) & 1u)) >> 16;
  return (unsigned short)r;
}
__device__ __forceinline__ float bf2f(unsigned short u) {
  uint32_t v = ((uint32_t)u) << 16;
  return __builtin_bit_cast(float, v);
}

__device__ __forceinline__ void gl2lds16(const void* g, void* l) {
  __builtin_amdgcn_global_load_lds((__attribute__((address_space(1))) void*)g,
                                   (__attribute__((address_space(3))) void*)l,
                                   16, 0, 0);
}

// ---------------- fp32 -> bf16 cast (vectorized, 8 elems/thread) -------------
__global__ void cvt_f32_bf16(const float* __restrict__ src,
                             unsigned short* __restrict__ dst, size_t n) {
  size_t i = ((size_t)blockIdx.x * blockDim.x + threadIdx.x) * 8;
  if (i >= n) return;
  float4 a = *(const float4*)(src + i);
  float4 b = *(const float4*)(src + i + 4);
  typedef __attribute__((ext_vector_type(8))) unsigned short u16x8;
  u16x8 o;
  o[0] = f2bf(a.x); o[1] = f2bf(a.y); o[2] = f2bf(a.z); o[3] = f2bf(a.w);
  o[4] = f2bf(b.x); o[5] = f2bf(b.y); o[6] = f2bf(b.z); o[7] = f2bf(b.w);
  *(u16x8*)(dst + i) = o;
}

// ---------------- x [B,4096,384] f32 -> xT [B,384,4096] bf16 -----------------
__global__ __launch_bounds__(256)
void transpose_x(const float* __restrict__ x, unsigned short* __restrict__ xT) {
  __shared__ float tile[64 * 65];
  int b = blockIdx.z;
  int n0 = blockIdx.x * 64;
  int c0 = blockIdx.y * 64;
  int t = threadIdx.x;
  const float* xb = x + (size_t)b * N_ * C_;
  #pragma unroll
  for (int i = 0; i < 16; i++) {
    int r = i * 4 + (t >> 6);   // row within n-tile
    int cc = t & 63;            // col within c-tile
    tile[r * 65 + cc] = xb[(size_t)(n0 + r) * C_ + c0 + cc];
  }
  __syncthreads();
  unsigned short* xTb = xT + (size_t)b * C_ * N_;
  #pragma unroll
  for (int i = 0; i < 16; i++) {
    int r = i * 4 + (t >> 6);   // row within c-tile (output row)
    int nn = t & 63;            // col within n-tile
    xTb[(size_t)(c0 + r) * N_ + n0 + nn] = f2bf(tile[nn * 65 + r]);
  }
}

// ---------------- BT-GEMM: Out[b] = A @ Bt[b]^T (+bias) ----------------------
// A   [MA, 4096] bf16 row-major (K-contiguous)
// Bt  [.., 384, 4096] bf16 per-batch (K-contiguous)  -> logical B[k][c]
// Out bf16 [MA,384] (no bias) or f32 [MA,384] (+bias[m])
// Tile 128x128, BK=64, 4 waves each 64x64 via 4x4 of 16x16x32 MFMA.
// LDS XOR-swizzle: chunk slot(r, c8) = r*8 + (c8 ^ (r&7)); staging stays
// lane-contiguous (global_load_lds requirement), frag ds_read_b128 <=2-way.
template <bool BIAS>
__global__ __launch_bounds__(256, 2)
void gemm_bt(const unsigned short* __restrict__ A,
             const unsigned short* __restrict__ Bt,
             void* __restrict__ OutV,
             const float* __restrict__ bias,
             size_t bStride, size_t outStride) {
  __shared__ unsigned short As[128 * 64];
  __shared__ unsigned short Bs[128 * 64];
  const int b  = blockIdx.x;          // batch fastest: 16 blocks share A-tile
  const int m0 = blockIdx.y * 128;
  const int c0 = blockIdx.z * 128;
  const int t = threadIdx.x;
  const int lane = t & 63;
  const int w = t >> 6;
  const int wm = (w & 1) * 64;
  const int wn = (w >> 1) * 64;
  const int quad = lane >> 4;
  const int r16  = lane & 15;

  const unsigned short* Bb = Bt + (size_t)b * bStride;

  f32x4 acc[4][4];
  #pragma unroll
  for (int i = 0; i < 4; i++)
    #pragma unroll
    for (int j = 0; j < 4; j++)
      acc[i][j] = (f32x4){0.f, 0.f, 0.f, 0.f};

  const int rs = t >> 3;                    // staging row 0..31
  const int q8 = (t & 7) ^ (rs & 7);        // swizzled logical k-chunk
  const unsigned short* aSrc = A  + (size_t)(m0 + rs) * 4096 + q8 * 8;
  const unsigned short* bSrc = Bb + (size_t)(c0 + rs) * 4096 + q8 * 8;
  unsigned short* aDst = As + t * 8;
  unsigned short* bDst = Bs + t * 8;

  for (int k0 = 0; k0 < 4096; k0 += 64) {
    #pragma unroll
    for (int p = 0; p < 4; p++) {
      gl2lds16(aSrc + (size_t)p * 32 * 4096 + k0, aDst + p * 2048);
      gl2lds16(bSrc + (size_t)p * 32 * 4096 + k0, bDst + p * 2048);
    }
    __syncthreads();
    #pragma unroll
    for (int kk = 0; kk < 2; kk++) {
      short8 af[4], bfv[4];
      const int cb = kk * 4 + quad;         // logical chunk index 0..7
      #pragma unroll
      for (int i = 0; i < 4; i++) {
        int ra = wm + i * 16 + r16;
        af[i]  = *(const short8*)(As + ra * 64 + ((cb ^ (ra & 7)) * 8));
        int rb = wn + i * 16 + r16;
        bfv[i] = *(const short8*)(Bs + rb * 64 + ((cb ^ (rb & 7)) * 8));
      }
      #pragma unroll
      for (int i = 0; i < 4; i++)
        #pragma unroll
        for (int j = 0; j < 4; j++)
          acc[i][j] = __builtin_amdgcn_mfma_f32_16x16x32_bf16(
              af[i], bfv[j], acc[i][j], 0, 0, 0);
    }
    __syncthreads();
  }

  // Epilogue. C/D layout: col = lane&15, row = quad*4 + reg.
  if (BIAS) {
    float* Out = (float*)OutV + (size_t)b * outStride;
    #pragma unroll
    for (int i = 0; i < 4; i++) {
      #pragma unroll
      for (int v = 0; v < 4; v++) {
        int m = m0 + wm + i * 16 + quad * 4 + v;
        float bi = bias[m];
        #pragma unroll
        for (int j = 0; j < 4; j++) {
          int c = c0 + wn + j * 16 + r16;
          Out[(size_t)m * C_ + c] = acc[i][j][v] + bi;
        }
      }
    }
  } else {
    unsigned short* Out = (unsigned short*)OutV + (size_t)b * outStride;
    #pragma unroll
    for (int i = 0; i < 4; i++) {
      #pragma unroll
      for (int v = 0; v < 4; v++) {
        int m = m0 + wm + i * 16 + quad * 4 + v;
        #pragma unroll
        for (int j = 0; j < 4; j++) {
          int c = c0 + wn + j * 16 + r16;
          Out[(size_t)m * C_ + c] = f2bf(acc[i][j][v]);
        }
      }
    }
  }
}

// ---------------- middle: norms + kernel-trick + gelu -> GT ------------------
// Y[b] bf16 [12288, 384]: rows 0..4095 q, 4096..8191 k, 8192..12287 v
//   (row m = h*512 + n' within each third)
// GT[b] bf16 [384, 4096]: GT[c][h*512+n'] = gelu(qhat * kt)
__global__ __launch_bounds__(512)
void middle(const unsigned short* __restrict__ Y,
            unsigned short* __restrict__ GT,
            const float* __restrict__ scale) {
  const int h = blockIdx.x;
  const int b = blockIdx.y;
  const unsigned short* Yb = Y + (size_t)b * 12288 * C_;
  const unsigned short* Q = Yb + (size_t)(h * NH_) * C_;
  const unsigned short* K = Yb + (size_t)(N_ + h * NH_) * C_;
  const unsigned short* V = Yb + (size_t)(2 * N_ + h * NH_) * C_;
  unsigned short* GTb = GT + (size_t)b * C_ * N_ + h * NH_;

  __shared__ float invq[C_], invk[C_], kt[NH_];
  const int t = threadIdx.x;
  const float sc = scale[h];

  // Phase A: per-column (c) sum of squares over 512 rows
  if (t < C_) {
    float sq = 0.f, sk = 0.f;
    for (int n = 0; n < NH_; n++) {
      float qv = bf2f(Q[(size_t)n * C_ + t]);
      float kv = bf2f(K[(size_t)n * C_ + t]);
      sq += qv * qv;
      sk += kv * kv;
    }
    invq[t] = rsqrtf(sq);
    invk[t] = rsqrtf(sk);
  }
  __syncthreads();

  // Phase B: kt[n'] = scale * sum_c khat[n'][c] * v[n'][c]
  {
    int w = t >> 6, l = t & 63;
    for (int n = w; n < NH_; n += 8) {
      float s = 0.f;
      for (int c = l; c < C_; c += 64)
        s += bf2f(K[(size_t)n * C_ + c]) * invk[c] * bf2f(V[(size_t)n * C_ + c]);
      #pragma unroll
      for (int o = 32; o > 0; o >>= 1) s += __shfl_xor(s, o);
      if (l == 0) kt[n] = s * sc;
    }
  }
  __syncthreads();

  // Phase C: GT[c][h*512+n] = gelu(qhat[n][c] * kt[n]); coalesced writes over n
  {
    int n = t;  // 512 threads
    float ktv = kt[n];
    for (int c = 0; c < C_; c++) {
      float xv = bf2f(Q[(size_t)n * C_ + c]) * invq[c] * ktv;
      float g = 0.5f * xv * (1.0f + erff(xv * 0.70710678118654752f));
      GTb[(size_t)c * N_ + n] = f2bf(g);
    }
  }
}

extern "C" void kernel_launch(void* const* d_in, const int* in_sizes, int n_in,
                              void* d_out, int out_size, void* d_ws, size_t ws_size,
                              hipStream_t stream) {
  const float* x     = (const float*)d_in[0];
  const float* wq    = (const float*)d_in[1];
  const float* wkv   = (const float*)d_in[2];
  const float* wproj = (const float*)d_in[3];
  const float* bproj = (const float*)d_in[4];
  const float* scale = (const float*)d_in[5];

  // Workspace layout (bf16 buffers), total ~386 MB
  unsigned short* Wqkv = (unsigned short*)d_ws;                 // [12288,4096]
  unsigned short* Wp   = Wqkv + (size_t)12288 * 4096;           // [4096,4096]
  unsigned short* xT   = Wp   + (size_t)4096 * 4096;            // [16,384,4096]
  unsigned short* Y    = xT   + (size_t)B_ * C_ * N_;           // [16,12288,384]
  unsigned short* GT   = Y    + (size_t)B_ * 12288 * C_;        // [16,384,4096]

  const size_t nq  = (size_t)4096 * 4096;
  const size_t nkv = (size_t)8192 * 4096;

  cvt_f32_bf16<<<(int)(nq  / 8 / 256), 256, 0, stream>>>(wq,    Wqkv,      nq);
  cvt_f32_bf16<<<(int)(nkv / 8 / 256), 256, 0, stream>>>(wkv,   Wqkv + nq, nkv);
  cvt_f32_bf16<<<(int)(nq  / 8 / 256), 256, 0, stream>>>(wproj, Wp,        nq);

  transpose_x<<<dim3(64, 6, 16), 256, 0, stream>>>(x, xT);

  // GEMM1: Y[b] = Wqkv @ xT[b]^T   (bf16 out)
  gemm_bt<false><<<dim3(16, 96, 3), 256, 0, stream>>>(
      Wqkv, xT, Y, nullptr, (size_t)C_ * N_, (size_t)12288 * C_);

  middle<<<dim3(8, 16), 512, 0, stream>>>(Y, GT, scale);

  // GEMM2: out[b] = Wproj @ GT[b]^T + bproj  (fp32 out, final layout [B,N,C])
  gemm_bt<true><<<dim3(16, 32, 3), 256, 0, stream>>>(
      Wp, GT, d_out, bproj, (size_t)C_ * N_, (size_t)N_ * C_);
}